// Round 9
// baseline (185.955 us; speedup 1.0000x reference)
//
#include <hip/hip_runtime.h>
#include <hip/hip_bf16.h>

typedef float f32x4 __attribute__((ext_vector_type(4)));

namespace {
constexpr int V_     = 6;
constexpr int DIM_   = 384;
constexpr int PH_    = 37;
constexpr int PW_    = 37;
constexpr int PP_    = PH_ * PW_;      // 1369
constexpr int NBV_   = 12;             // B*V
constexpr int ZROW_  = NBV_ * PP_;     // sentinel row index (all zeros)
constexpr float FPATCH_ = 14.0f;
constexpr float FIMG_   = 518.0f;      // H == W == 37*14

constexpr int TPX_ = (PP_ + 31) / 32;  // 43 patch tiles
constexpr int TPY_ = DIM_ / 32;        // 12 dim tiles
constexpr int TPB_ = TPX_ * TPY_;      // 516 transpose blocks per bv
constexpr int TP_TOTAL_ = TPB_ * NBV_; // 6192 transpose blocks
constexpr int GPB_ = 32;               // points per gather block
}

// ---------------------------------------------------------------------------
// Kernel A: blocks [0, TP_TOTAL_) transpose dino (12,384,1369) f32 ->
//           tdino (12*1369+1, 384) bf16; block TP_TOTAL_ zeroes the sentinel.
// ---------------------------------------------------------------------------
__global__ __launch_bounds__(256)
void prep_kernel(const float* __restrict__ dino,
                 __hip_bfloat16* __restrict__ tdino) {
    int blk = blockIdx.x;
    int t   = threadIdx.x;

    if (blk >= TP_TOTAL_) {                          // ---- zero sentinel row
        __hip_bfloat16* zrow = tdino + (size_t)ZROW_ * DIM_;
        if (t < DIM_ / 2)
            reinterpret_cast<uint*>(zrow)[t] = 0u;   // 2 bf16 per store
        return;
    }

    __shared__ float tile[32][33];                   // [d_local][p_local]
    int tx = t & 31, ty = t >> 5;                    // (32, 8)
    int bv  = blk / TPB_;
    int rem = blk % TPB_;
    int p0  = (rem % TPX_) * 32;                     // patch tile origin
    int d0  = (rem / TPX_) * 32;                     // dim tile origin
    const float* in = dino + (size_t)bv * DIM_ * PP_;
    __hip_bfloat16* out = tdino + (size_t)bv * PP_ * DIM_;
#pragma unroll
    for (int k = 0; k < 4; k++) {
        int d = d0 + ty + k * 8;                     // always < 384
        int p = p0 + tx;
        if (p < PP_) tile[ty + k * 8][tx] = in[(size_t)d * PP_ + p];
    }
    __syncthreads();
    // write phase: 512 (p_local, d-pair) cells, 2 iterations x 256 threads.
#pragma unroll
    for (int w = 0; w < 2; w++) {
        int lin = w * 256 + t;                       // 0..511
        int pl  = lin >> 4;                          // 0..31  p_local
        int dp  = lin & 15;                          // 0..15  d-pair
        int p   = p0 + pl;
        if (p < PP_) {
            __hip_bfloat162 v;
            v.x = __float2bfloat16(tile[2 * dp + 0][pl]);
            v.y = __float2bfloat16(tile[2 * dp + 1][pl]);
            *reinterpret_cast<__hip_bfloat162*>(
                out + (size_t)p * DIM_ + d0 + 2 * dp) = v;
        }
    }
}

// ---------------------------------------------------------------------------
// Kernel B: fused project + gather. Block = 256 threads, GPB_=32 points.
//   1) threads [0,144) build sP = K @ E[:3,:] in LDS; [144,192) copy E row 2
//   2) threads [0,GPB_) project their point -> patch row (ZROW_ if invalid)
//   3) stream: 6 iters; per iter each thread loads 16B (8 bf16, b128),
//      converts, issues two f32x4 nontemporal stores (32B out/lane/iter)
// ---------------------------------------------------------------------------
__global__ __launch_bounds__(256)
void gather_fused(const float* __restrict__ pts,
                  const int* __restrict__ bi,
                  const float* __restrict__ intr,
                  const float* __restrict__ extr,
                  const __hip_bfloat16* __restrict__ tdino,
                  float* __restrict__ out, int N) {
    __shared__ float sP[NBV_ * 12];
    __shared__ float sR[NBV_ * 4];
    __shared__ int   soff[GPB_];

    int t  = threadIdx.x;
    int n0 = blockIdx.x * GPB_;

    if (t < NBV_ * 12) {
        int m = t / 12, e = t % 12, i = e >> 2, k = e & 3;
        const float* K = intr + m * 9;
        const float* E = extr + m * 16;
        sP[t] = K[i*3+0]*E[0*4+k] + K[i*3+1]*E[1*4+k] + K[i*3+2]*E[2*4+k];
    } else if (t < NBV_ * 12 + NBV_ * 4) {
        int u = t - NBV_ * 12;
        int m = u >> 2, k = u & 3;
        sR[u] = extr[m*16 + 8 + k];
    }
    __syncthreads();

    if (t < GPB_) {
        int n = n0 + t;
        int result = ZROW_;
        if (n < N) {
            float x = pts[n*3+0], y = pts[n*3+1], z = pts[n*3+2];
            int b = bi[n];
#pragma unroll
            for (int v = 0; v < V_; v++) {
                int m = b * V_ + v;
                const float* P = sP + m * 12;
                const float* r = sR + m * 4;
                float pc0   = P[0]*x + P[1]*y + P[2]*z  + P[3];
                float pc1   = P[4]*x + P[5]*y + P[6]*z  + P[7];
                float w     = P[8]*x + P[9]*y + P[10]*z + P[11];
                float depth = r[0]*x + r[1]*y + r[2]*z  + r[3];
                float u  = pc0 / w;
                float vc = pc1 / w;
                bool valid = (depth > 0.1f) && (u >= 0.0f) && (u < FIMG_)
                                            && (vc >= 0.0f) && (vc < FIMG_);
                if (valid) {
                    int up = (int)floorf(u  / FPATCH_);
                    int vp = (int)floorf(vc / FPATCH_);
                    up = min(max(up, 0), PW_ - 1);
                    vp = min(max(vp, 0), PH_ - 1);
                    result = m * PP_ + vp * PW_ + up;   // max valid v wins
                }
            }
        }
        soff[t] = result;
    }
    __syncthreads();

    // 32 pts x 48 16B-load-units = 1536; /256 threads = 6 iterations
#pragma unroll
    for (int i = 0; i < (GPB_ * 48) / 256; i++) {
        int idx2 = i * 256 + t;                       // 0 .. GPB_*48
        int nl   = idx2 / 48;                         // local point
        int cc   = idx2 - nl * 48;                    // 16B unit within row
        int n    = n0 + nl;
        if (n >= N) break;                            // monotone per-thread
        // load 8 bf16 (16B), branch-free via sentinel row
        uint4 raw = *reinterpret_cast<const uint4*>(
            tdino + (size_t)soff[nl] * DIM_ + cc * 8);
        f32x4 lo, hi;
        lo.x = __uint_as_float((raw.x & 0xFFFFu) << 16);
        lo.y = __uint_as_float((raw.x & 0xFFFF0000u));
        lo.z = __uint_as_float((raw.y & 0xFFFFu) << 16);
        lo.w = __uint_as_float((raw.y & 0xFFFF0000u));
        hi.x = __uint_as_float((raw.z & 0xFFFFu) << 16);
        hi.y = __uint_as_float((raw.z & 0xFFFF0000u));
        hi.z = __uint_as_float((raw.w & 0xFFFFu) << 16);
        hi.w = __uint_as_float((raw.w & 0xFFFF0000u));
        f32x4* dst = reinterpret_cast<f32x4*>(out) + (size_t)n * 96 + cc * 2;
        __builtin_nontemporal_store(lo, dst);
        __builtin_nontemporal_store(hi, dst + 1);
    }
}

// ---------------------------------------------------------------------------
// Fallback (ws too small): fully inline, strided gather from native dino.
// ---------------------------------------------------------------------------
__global__ void fallback_kernel(const float* __restrict__ pts,
                                const int* __restrict__ bi,
                                const float* __restrict__ intr,
                                const float* __restrict__ extr,
                                const float* __restrict__ dino,
                                float* __restrict__ out, int N) {
    int gid = blockIdx.x * blockDim.x + threadIdx.x;
    int n = gid / 96;
    int c = gid - n * 96;
    if (n >= N) return;
    float x = pts[n*3+0], y = pts[n*3+1], z = pts[n*3+2];
    int b = bi[n];
    int sel = -1; int selp = 0;
    for (int v = 0; v < V_; v++) {
        int m = b * V_ + v;
        const float* K = intr + m * 9;
        const float* E = extr + m * 16;
        float P0[4], P1[4], P2[4];
#pragma unroll
        for (int k = 0; k < 4; k++) {
            P0[k] = K[0]*E[0*4+k] + K[1]*E[1*4+k] + K[2]*E[2*4+k];
            P1[k] = K[3]*E[0*4+k] + K[4]*E[1*4+k] + K[5]*E[2*4+k];
            P2[k] = K[6]*E[0*4+k] + K[7]*E[1*4+k] + K[8]*E[2*4+k];
        }
        float pc0   = P0[0]*x + P0[1]*y + P0[2]*z + P0[3];
        float pc1   = P1[0]*x + P1[1]*y + P1[2]*z + P1[3];
        float w     = P2[0]*x + P2[1]*y + P2[2]*z + P2[3];
        float depth = E[8]*x + E[9]*y + E[10]*z + E[11];
        float u  = pc0 / w;
        float vc = pc1 / w;
        bool valid = (depth > 0.1f) && (u >= 0.0f) && (u < FIMG_)
                                    && (vc >= 0.0f) && (vc < FIMG_);
        if (valid) {
            int up = (int)floorf(u  / FPATCH_);
            int vp = (int)floorf(vc / FPATCH_);
            up = min(max(up, 0), PW_ - 1);
            vp = min(max(vp, 0), PH_ - 1);
            sel = v;
            selp = m * PP_ + vp * PW_ + up;
        }
    }
    float4 val = make_float4(0.f, 0.f, 0.f, 0.f);
    if (sel >= 0) {
        int bvbase = (selp / PP_) * DIM_;
        int p      = selp % PP_;
        int d = c * 4;
        val.x = dino[(size_t)(bvbase + d + 0) * PP_ + p];
        val.y = dino[(size_t)(bvbase + d + 1) * PP_ + p];
        val.z = dino[(size_t)(bvbase + d + 2) * PP_ + p];
        val.w = dino[(size_t)(bvbase + d + 3) * PP_ + p];
    }
    reinterpret_cast<float4*>(out)[(size_t)n * 96 + c] = val;
}

extern "C" void kernel_launch(void* const* d_in, const int* in_sizes, int n_in,
                              void* d_out, int out_size, void* d_ws, size_t ws_size,
                              hipStream_t stream) {
    const float* pts  = (const float*)d_in[0];   // (N,3)
    // d_in[1] = imgs (unused)
    const float* intr = (const float*)d_in[2];   // (2,6,3,3)
    const float* extr = (const float*)d_in[3];   // (2,6,4,4)
    const float* dino = (const float*)d_in[4];   // (2,6,384,37,37)
    const int*   bi   = (const int*)d_in[5];     // (N,)
    float* out = (float*)d_out;

    const int N = in_sizes[5];                   // 250000

    // workspace: tdino bf16, (12*1369+1) rows x 384, 16B-aligned at base
    const size_t tdino_bytes = ((size_t)NBV_ * PP_ + 1) * DIM_ * 2;

    if (ws_size >= tdino_bytes) {
        __hip_bfloat16* tdino = (__hip_bfloat16*)d_ws;

        prep_kernel<<<TP_TOTAL_ + 1, 256, 0, stream>>>(dino, tdino);
        int gblocks = (N + GPB_ - 1) / GPB_;
        gather_fused<<<gblocks, 256, 0, stream>>>(pts, bi, intr, extr, tdino,
                                                  out, N);
    } else {
        const int total = N * 96;
        fallback_kernel<<<(total + 255) / 256, 256, 0, stream>>>(
            pts, bi, intr, extr, dino, out, N);
    }
}

// Round 10
// 89.775 us; speedup vs baseline: 2.0714x; 2.0714x over previous
//
#include <hip/hip_runtime.h>
#include <hip/hip_bf16.h>

typedef float f32x4 __attribute__((ext_vector_type(4)));

namespace {
constexpr int V_     = 6;
constexpr int DIM_   = 384;
constexpr int PH_    = 37;
constexpr int PW_    = 37;
constexpr int PP_    = PH_ * PW_;      // 1369
constexpr int NBV_   = 12;             // B*V
constexpr int ZROW_  = NBV_ * PP_;     // sentinel row index (all zeros)
constexpr float FPATCH_ = 14.0f;
constexpr float FIMG_   = 518.0f;      // H == W == 37*14

constexpr int TPX_ = (PP_ + 31) / 32;  // 43 patch tiles
constexpr int TPY_ = DIM_ / 32;        // 12 dim tiles
constexpr int TPB_ = TPX_ * TPY_;      // 516 transpose blocks per bv
constexpr int TP_TOTAL_ = TPB_ * NBV_; // 6192 transpose blocks
constexpr int GPB_ = 32;               // points per gather block (A/B vs 16)
}

// ---------------------------------------------------------------------------
// Kernel A: blocks [0, TP_TOTAL_) transpose dino (12,384,1369) f32 ->
//           tdino (12*1369+1, 384) bf16; block TP_TOTAL_ zeroes the sentinel.
// ---------------------------------------------------------------------------
__global__ __launch_bounds__(256)
void prep_kernel(const float* __restrict__ dino,
                 __hip_bfloat16* __restrict__ tdino) {
    int blk = blockIdx.x;
    int t   = threadIdx.x;

    if (blk >= TP_TOTAL_) {                          // ---- zero sentinel row
        __hip_bfloat16* zrow = tdino + (size_t)ZROW_ * DIM_;
        if (t < DIM_ / 2)
            reinterpret_cast<uint*>(zrow)[t] = 0u;   // 2 bf16 per store
        return;
    }

    __shared__ float tile[32][33];                   // [d_local][p_local]
    int tx = t & 31, ty = t >> 5;                    // (32, 8)
    int bv  = blk / TPB_;
    int rem = blk % TPB_;
    int p0  = (rem % TPX_) * 32;                     // patch tile origin
    int d0  = (rem / TPX_) * 32;                     // dim tile origin
    const float* in = dino + (size_t)bv * DIM_ * PP_;
    __hip_bfloat16* out = tdino + (size_t)bv * PP_ * DIM_;
#pragma unroll
    for (int k = 0; k < 4; k++) {
        int d = d0 + ty + k * 8;                     // always < 384
        int p = p0 + tx;
        if (p < PP_) tile[ty + k * 8][tx] = in[(size_t)d * PP_ + p];
    }
    __syncthreads();
    // write phase: 512 (p_local, d-pair) cells, 2 iterations x 256 threads.
#pragma unroll
    for (int w = 0; w < 2; w++) {
        int lin = w * 256 + t;                       // 0..511
        int pl  = lin >> 4;                          // 0..31  p_local
        int dp  = lin & 15;                          // 0..15  d-pair
        int p   = p0 + pl;
        if (p < PP_) {
            __hip_bfloat162 v;
            v.x = __float2bfloat16(tile[2 * dp + 0][pl]);
            v.y = __float2bfloat16(tile[2 * dp + 1][pl]);
            *reinterpret_cast<__hip_bfloat162*>(
                out + (size_t)p * DIM_ + d0 + 2 * dp) = v;
        }
    }
}

// ---------------------------------------------------------------------------
// Kernel B: fused project + gather. Block = 256 threads, GPB_=32 points.
// Round-7 stream shape: per iter each lane loads 4 bf16 (8B) and issues ONE
// contiguous 16B nt-store (lane i -> base + i*16B, dense 1KB/wave/instr).
// ---------------------------------------------------------------------------
__global__ __launch_bounds__(256)
void gather_fused(const float* __restrict__ pts,
                  const int* __restrict__ bi,
                  const float* __restrict__ intr,
                  const float* __restrict__ extr,
                  const __hip_bfloat16* __restrict__ tdino,
                  float* __restrict__ out, int N) {
    __shared__ float sP[NBV_ * 12];
    __shared__ float sR[NBV_ * 4];
    __shared__ int   soff[GPB_];

    int t  = threadIdx.x;
    int n0 = blockIdx.x * GPB_;

    if (t < NBV_ * 12) {
        int m = t / 12, e = t % 12, i = e >> 2, k = e & 3;
        const float* K = intr + m * 9;
        const float* E = extr + m * 16;
        sP[t] = K[i*3+0]*E[0*4+k] + K[i*3+1]*E[1*4+k] + K[i*3+2]*E[2*4+k];
    } else if (t < NBV_ * 12 + NBV_ * 4) {
        int u = t - NBV_ * 12;
        int m = u >> 2, k = u & 3;
        sR[u] = extr[m*16 + 8 + k];
    }
    __syncthreads();

    if (t < GPB_) {
        int n = n0 + t;
        int result = ZROW_;
        if (n < N) {
            float x = pts[n*3+0], y = pts[n*3+1], z = pts[n*3+2];
            int b = bi[n];
#pragma unroll
            for (int v = 0; v < V_; v++) {
                int m = b * V_ + v;
                const float* P = sP + m * 12;
                const float* r = sR + m * 4;
                float pc0   = P[0]*x + P[1]*y + P[2]*z  + P[3];
                float pc1   = P[4]*x + P[5]*y + P[6]*z  + P[7];
                float w     = P[8]*x + P[9]*y + P[10]*z + P[11];
                float depth = r[0]*x + r[1]*y + r[2]*z  + r[3];
                float u  = pc0 / w;
                float vc = pc1 / w;
                bool valid = (depth > 0.1f) && (u >= 0.0f) && (u < FIMG_)
                                            && (vc >= 0.0f) && (vc < FIMG_);
                if (valid) {
                    int up = (int)floorf(u  / FPATCH_);
                    int vp = (int)floorf(vc / FPATCH_);
                    up = min(max(up, 0), PW_ - 1);
                    vp = min(max(vp, 0), PH_ - 1);
                    result = m * PP_ + vp * PW_ + up;   // max valid v wins
                }
            }
        }
        soff[t] = result;
    }
    __syncthreads();

#pragma unroll
    for (int i = 0; i < (GPB_ * 96) / 256; i++) {     // 12 iterations
        int idx = i * 256 + t;                        // 0 .. GPB_*96
        int nl  = idx / 96;
        int c   = idx - nl * 96;                      // f32x4 chunk in row
        int n   = n0 + nl;
        if (n >= N) break;                            // never taken, N%32==0
        // load 4 bf16 (8B), branch-free via sentinel row
        uint2 raw = *reinterpret_cast<const uint2*>(
            tdino + (size_t)soff[nl] * DIM_ + c * 4);
        f32x4 val;
        val.x = __uint_as_float((raw.x & 0xFFFFu) << 16);
        val.y = __uint_as_float((raw.x & 0xFFFF0000u));
        val.z = __uint_as_float((raw.y & 0xFFFFu) << 16);
        val.w = __uint_as_float((raw.y & 0xFFFF0000u));
        __builtin_nontemporal_store(
            val, reinterpret_cast<f32x4*>(out) + (size_t)n * 96 + c);
    }
}

// ---------------------------------------------------------------------------
// Fallback (ws too small): fully inline, strided gather from native dino.
// ---------------------------------------------------------------------------
__global__ void fallback_kernel(const float* __restrict__ pts,
                                const int* __restrict__ bi,
                                const float* __restrict__ intr,
                                const float* __restrict__ extr,
                                const float* __restrict__ dino,
                                float* __restrict__ out, int N) {
    int gid = blockIdx.x * blockDim.x + threadIdx.x;
    int n = gid / 96;
    int c = gid - n * 96;
    if (n >= N) return;
    float x = pts[n*3+0], y = pts[n*3+1], z = pts[n*3+2];
    int b = bi[n];
    int sel = -1; int selp = 0;
    for (int v = 0; v < V_; v++) {
        int m = b * V_ + v;
        const float* K = intr + m * 9;
        const float* E = extr + m * 16;
        float P0[4], P1[4], P2[4];
#pragma unroll
        for (int k = 0; k < 4; k++) {
            P0[k] = K[0]*E[0*4+k] + K[1]*E[1*4+k] + K[2]*E[2*4+k];
            P1[k] = K[3]*E[0*4+k] + K[4]*E[1*4+k] + K[5]*E[2*4+k];
            P2[k] = K[6]*E[0*4+k] + K[7]*E[1*4+k] + K[8]*E[2*4+k];
        }
        float pc0   = P0[0]*x + P0[1]*y + P0[2]*z + P0[3];
        float pc1   = P1[0]*x + P1[1]*y + P1[2]*z + P1[3];
        float w     = P2[0]*x + P2[1]*y + P2[2]*z + P2[3];
        float depth = E[8]*x + E[9]*y + E[10]*z + E[11];
        float u  = pc0 / w;
        float vc = pc1 / w;
        bool valid = (depth > 0.1f) && (u >= 0.0f) && (u < FIMG_)
                                    && (vc >= 0.0f) && (vc < FIMG_);
        if (valid) {
            int up = (int)floorf(u  / FPATCH_);
            int vp = (int)floorf(vc / FPATCH_);
            up = min(max(up, 0), PW_ - 1);
            vp = min(max(vp, 0), PH_ - 1);
            sel = v;
            selp = m * PP_ + vp * PW_ + up;
        }
    }
    float4 val = make_float4(0.f, 0.f, 0.f, 0.f);
    if (sel >= 0) {
        int bvbase = (selp / PP_) * DIM_;
        int p      = selp % PP_;
        int d = c * 4;
        val.x = dino[(size_t)(bvbase + d + 0) * PP_ + p];
        val.y = dino[(size_t)(bvbase + d + 1) * PP_ + p];
        val.z = dino[(size_t)(bvbase + d + 2) * PP_ + p];
        val.w = dino[(size_t)(bvbase + d + 3) * PP_ + p];
    }
    reinterpret_cast<float4*>(out)[(size_t)n * 96 + c] = val;
}

extern "C" void kernel_launch(void* const* d_in, const int* in_sizes, int n_in,
                              void* d_out, int out_size, void* d_ws, size_t ws_size,
                              hipStream_t stream) {
    const float* pts  = (const float*)d_in[0];   // (N,3)
    // d_in[1] = imgs (unused)
    const float* intr = (const float*)d_in[2];   // (2,6,3,3)
    const float* extr = (const float*)d_in[3];   // (2,6,4,4)
    const float* dino = (const float*)d_in[4];   // (2,6,384,37,37)
    const int*   bi   = (const int*)d_in[5];     // (N,)
    float* out = (float*)d_out;

    const int N = in_sizes[5];                   // 250000

    // workspace: tdino bf16, (12*1369+1) rows x 384, aligned at base
    const size_t tdino_bytes = ((size_t)NBV_ * PP_ + 1) * DIM_ * 2;

    if (ws_size >= tdino_bytes) {
        __hip_bfloat16* tdino = (__hip_bfloat16*)d_ws;

        prep_kernel<<<TP_TOTAL_ + 1, 256, 0, stream>>>(dino, tdino);
        int gblocks = (N + GPB_ - 1) / GPB_;
        gather_fused<<<gblocks, 256, 0, stream>>>(pts, bi, intr, extr, tdino,
                                                  out, N);
    } else {
        const int total = N * 96;
        fallback_kernel<<<(total + 255) / 256, 256, 0, stream>>>(
            pts, bi, intr, extr, dino, out, N);
    }
}

// Round 11
// 87.523 us; speedup vs baseline: 2.1246x; 1.0257x over previous
//
#include <hip/hip_runtime.h>
#include <hip/hip_bf16.h>

typedef float f32x4 __attribute__((ext_vector_type(4)));

namespace {
constexpr int V_     = 6;
constexpr int DIM_   = 384;
constexpr int PH_    = 37;
constexpr int PW_    = 37;
constexpr int PP_    = PH_ * PW_;      // 1369
constexpr int NBV_   = 12;             // B*V
constexpr int ZROW_  = NBV_ * PP_;     // sentinel row index (all zeros)
constexpr float FPATCH_ = 14.0f;
constexpr float FIMG_   = 518.0f;      // H == W == 37*14

constexpr int TPX_ = (PP_ + 31) / 32;  // 43 patch tiles
constexpr int TPY_ = DIM_ / 32;        // 12 dim tiles
constexpr int TPB_ = TPX_ * TPY_;      // 516 transpose blocks per bv
constexpr int TP_TOTAL_ = TPB_ * NBV_; // 6192 transpose blocks
constexpr int GPB_ = 16;               // points per gather block (proven best)
}

// ---------------------------------------------------------------------------
// Kernel A: blocks [0, TP_TOTAL_) transpose dino (12,384,1369) f32 ->
//           tdino (12*1369+1, 384) bf16; block TP_TOTAL_ zeroes the sentinel.
// ---------------------------------------------------------------------------
__global__ __launch_bounds__(256)
void prep_kernel(const float* __restrict__ dino,
                 __hip_bfloat16* __restrict__ tdino) {
    int blk = blockIdx.x;
    int t   = threadIdx.x;

    if (blk >= TP_TOTAL_) {                          // ---- zero sentinel row
        __hip_bfloat16* zrow = tdino + (size_t)ZROW_ * DIM_;
        if (t < DIM_ / 2)
            reinterpret_cast<uint*>(zrow)[t] = 0u;   // 2 bf16 per store
        return;
    }

    __shared__ float tile[32][33];                   // [d_local][p_local]
    int tx = t & 31, ty = t >> 5;                    // (32, 8)
    int bv  = blk / TPB_;
    int rem = blk % TPB_;
    int p0  = (rem % TPX_) * 32;                     // patch tile origin
    int d0  = (rem / TPX_) * 32;                     // dim tile origin
    const float* in = dino + (size_t)bv * DIM_ * PP_;
    __hip_bfloat16* out = tdino + (size_t)bv * PP_ * DIM_;
#pragma unroll
    for (int k = 0; k < 4; k++) {
        int d = d0 + ty + k * 8;                     // always < 384
        int p = p0 + tx;
        if (p < PP_) tile[ty + k * 8][tx] = in[(size_t)d * PP_ + p];
    }
    __syncthreads();
    // write phase: 512 (p_local, d-pair) cells, 2 iterations x 256 threads.
#pragma unroll
    for (int w = 0; w < 2; w++) {
        int lin = w * 256 + t;                       // 0..511
        int pl  = lin >> 4;                          // 0..31  p_local
        int dp  = lin & 15;                          // 0..15  d-pair
        int p   = p0 + pl;
        if (p < PP_) {
            __hip_bfloat162 v;
            v.x = __float2bfloat16(tile[2 * dp + 0][pl]);
            v.y = __float2bfloat16(tile[2 * dp + 1][pl]);
            *reinterpret_cast<__hip_bfloat162*>(
                out + (size_t)p * DIM_ + d0 + 2 * dp) = v;
        }
    }
}

// ---------------------------------------------------------------------------
// Kernel B: fused project + gather. Block = 256 threads, GPB_=16 points.
//   1) threads [0,144) build sP = K @ E[:3,:] in LDS; [144,192) copy E row 2
//   2) threads [0,GPB_) project their point -> patch row (ZROW_ if invalid)
//   3) stream: 6 iters; per iter each lane loads 4 bf16 (8B), converts,
//      issues ONE contiguous 16B nt-store (lane i -> base+i*16B, dense 1KB/wave)
// ---------------------------------------------------------------------------
__global__ __launch_bounds__(256)
void gather_fused(const float* __restrict__ pts,
                  const int* __restrict__ bi,
                  const float* __restrict__ intr,
                  const float* __restrict__ extr,
                  const __hip_bfloat16* __restrict__ tdino,
                  float* __restrict__ out, int N) {
    __shared__ float sP[NBV_ * 12];
    __shared__ float sR[NBV_ * 4];
    __shared__ int   soff[GPB_];

    int t  = threadIdx.x;
    int n0 = blockIdx.x * GPB_;

    if (t < NBV_ * 12) {
        int m = t / 12, e = t % 12, i = e >> 2, k = e & 3;
        const float* K = intr + m * 9;
        const float* E = extr + m * 16;
        sP[t] = K[i*3+0]*E[0*4+k] + K[i*3+1]*E[1*4+k] + K[i*3+2]*E[2*4+k];
    } else if (t < NBV_ * 12 + NBV_ * 4) {
        int u = t - NBV_ * 12;
        int m = u >> 2, k = u & 3;
        sR[u] = extr[m*16 + 8 + k];
    }
    __syncthreads();

    if (t < GPB_) {
        int n = n0 + t;
        int result = ZROW_;
        if (n < N) {
            float x = pts[n*3+0], y = pts[n*3+1], z = pts[n*3+2];
            int b = bi[n];
#pragma unroll
            for (int v = 0; v < V_; v++) {
                int m = b * V_ + v;
                const float* P = sP + m * 12;
                const float* r = sR + m * 4;
                float pc0   = P[0]*x + P[1]*y + P[2]*z  + P[3];
                float pc1   = P[4]*x + P[5]*y + P[6]*z  + P[7];
                float w     = P[8]*x + P[9]*y + P[10]*z + P[11];
                float depth = r[0]*x + r[1]*y + r[2]*z  + r[3];
                float u  = pc0 / w;
                float vc = pc1 / w;
                bool valid = (depth > 0.1f) && (u >= 0.0f) && (u < FIMG_)
                                            && (vc >= 0.0f) && (vc < FIMG_);
                if (valid) {
                    int up = (int)floorf(u  / FPATCH_);
                    int vp = (int)floorf(vc / FPATCH_);
                    up = min(max(up, 0), PW_ - 1);
                    vp = min(max(vp, 0), PH_ - 1);
                    result = m * PP_ + vp * PW_ + up;   // max valid v wins
                }
            }
        }
        soff[t] = result;
    }
    __syncthreads();

#pragma unroll
    for (int i = 0; i < (GPB_ * 96) / 256; i++) {     // 6 iterations
        int idx = i * 256 + t;                        // 0 .. GPB_*96
        int nl  = idx / 96;
        int c   = idx - nl * 96;                      // f32x4 chunk in row
        int n   = n0 + nl;
        if (n >= N) break;                            // never taken, N%16==0
        // load 4 bf16 (8B), branch-free via sentinel row
        uint2 raw = *reinterpret_cast<const uint2*>(
            tdino + (size_t)soff[nl] * DIM_ + c * 4);
        f32x4 val;
        val.x = __uint_as_float((raw.x & 0xFFFFu) << 16);
        val.y = __uint_as_float((raw.x & 0xFFFF0000u));
        val.z = __uint_as_float((raw.y & 0xFFFFu) << 16);
        val.w = __uint_as_float((raw.y & 0xFFFF0000u));
        __builtin_nontemporal_store(
            val, reinterpret_cast<f32x4*>(out) + (size_t)n * 96 + c);
    }
}

// ---------------------------------------------------------------------------
// Fallback (ws too small): fully inline, strided gather from native dino.
// ---------------------------------------------------------------------------
__global__ void fallback_kernel(const float* __restrict__ pts,
                                const int* __restrict__ bi,
                                const float* __restrict__ intr,
                                const float* __restrict__ extr,
                                const float* __restrict__ dino,
                                float* __restrict__ out, int N) {
    int gid = blockIdx.x * blockDim.x + threadIdx.x;
    int n = gid / 96;
    int c = gid - n * 96;
    if (n >= N) return;
    float x = pts[n*3+0], y = pts[n*3+1], z = pts[n*3+2];
    int b = bi[n];
    int sel = -1; int selp = 0;
    for (int v = 0; v < V_; v++) {
        int m = b * V_ + v;
        const float* K = intr + m * 9;
        const float* E = extr + m * 16;
        float P0[4], P1[4], P2[4];
#pragma unroll
        for (int k = 0; k < 4; k++) {
            P0[k] = K[0]*E[0*4+k] + K[1]*E[1*4+k] + K[2]*E[2*4+k];
            P1[k] = K[3]*E[0*4+k] + K[4]*E[1*4+k] + K[5]*E[2*4+k];
            P2[k] = K[6]*E[0*4+k] + K[7]*E[1*4+k] + K[8]*E[2*4+k];
        }
        float pc0   = P0[0]*x + P0[1]*y + P0[2]*z + P0[3];
        float pc1   = P1[0]*x + P1[1]*y + P1[2]*z + P1[3];
        float w     = P2[0]*x + P2[1]*y + P2[2]*z + P2[3];
        float depth = E[8]*x + E[9]*y + E[10]*z + E[11];
        float u  = pc0 / w;
        float vc = pc1 / w;
        bool valid = (depth > 0.1f) && (u >= 0.0f) && (u < FIMG_)
                                    && (vc >= 0.0f) && (vc < FIMG_);
        if (valid) {
            int up = (int)floorf(u  / FPATCH_);
            int vp = (int)floorf(vc / FPATCH_);
            up = min(max(up, 0), PW_ - 1);
            vp = min(max(vp, 0), PH_ - 1);
            sel = v;
            selp = m * PP_ + vp * PW_ + up;
        }
    }
    float4 val = make_float4(0.f, 0.f, 0.f, 0.f);
    if (sel >= 0) {
        int bvbase = (selp / PP_) * DIM_;
        int p      = selp % PP_;
        int d = c * 4;
        val.x = dino[(size_t)(bvbase + d + 0) * PP_ + p];
        val.y = dino[(size_t)(bvbase + d + 1) * PP_ + p];
        val.z = dino[(size_t)(bvbase + d + 2) * PP_ + p];
        val.w = dino[(size_t)(bvbase + d + 3) * PP_ + p];
    }
    reinterpret_cast<float4*>(out)[(size_t)n * 96 + c] = val;
}

extern "C" void kernel_launch(void* const* d_in, const int* in_sizes, int n_in,
                              void* d_out, int out_size, void* d_ws, size_t ws_size,
                              hipStream_t stream) {
    const float* pts  = (const float*)d_in[0];   // (N,3)
    // d_in[1] = imgs (unused)
    const float* intr = (const float*)d_in[2];   // (2,6,3,3)
    const float* extr = (const float*)d_in[3];   // (2,6,4,4)
    const float* dino = (const float*)d_in[4];   // (2,6,384,37,37)
    const int*   bi   = (const int*)d_in[5];     // (N,)
    float* out = (float*)d_out;

    const int N = in_sizes[5];                   // 250000

    // workspace: tdino bf16, (12*1369+1) rows x 384, aligned at base
    const size_t tdino_bytes = ((size_t)NBV_ * PP_ + 1) * DIM_ * 2;

    if (ws_size >= tdino_bytes) {
        __hip_bfloat16* tdino = (__hip_bfloat16*)d_ws;

        prep_kernel<<<TP_TOTAL_ + 1, 256, 0, stream>>>(dino, tdino);
        int gblocks = (N + GPB_ - 1) / GPB_;
        gather_fused<<<gblocks, 256, 0, stream>>>(pts, bi, intr, extr, tdino,
                                                  out, N);
    } else {
        const int total = N * 96;
        fallback_kernel<<<(total + 255) / 256, 256, 0, stream>>>(
            pts, bi, intr, extr, dino, out, N);
    }
}